// Round 9
// baseline (312.396 us; speedup 1.0000x reference)
//
#include <hip/hip_runtime.h>

#define HN 64
#define WN 64
#define HW 4096
#define CIN 256
#define COUT 256
#define NKK 9
#define OFFC 18
#define KTOT 2304          // 256*9, kk-major: k = kk*256 + c
#define CICH 32
#define SROW 296           // samp row stride bf16 (288+8 pad = 592 B = 37*16B, odd -> 2-way-free b128)
#define NCHUNK 8
#define PROD_T 768         // 12 producer waves

typedef __attribute__((ext_vector_type(8))) short bf16x8;
typedef __attribute__((ext_vector_type(4))) float f32x4;

// fp32 -> bf16 round-to-nearest-even (finite inputs)
static __device__ __forceinline__ unsigned short f2bf(float f) {
    unsigned u = __float_as_uint(f);
    return (unsigned short)((u + 0x7FFFu + ((u >> 16) & 1u)) >> 16);
}
static __device__ __forceinline__ unsigned pk2(float a, float b) {
    return (unsigned)f2bf(a) | ((unsigned)f2bf(b) << 16);
}
static __device__ __forceinline__ float bf2f(short s) {
    return __uint_as_float(((unsigned)(unsigned short)s) << 16);
}

// ---------------- Stage 0: prep — x -> NHWC bf16 + weight repack -----------
__global__ __launch_bounds__(256) void prep_kernel(
    const float* __restrict__ x, const float* __restrict__ w_dcn,
    const float* __restrict__ w_off, unsigned short* __restrict__ xh,
    unsigned short* __restrict__ wd_b, unsigned short* __restrict__ wo_b)
{
    const int blk = blockIdx.x;
    const int t = threadIdx.x;
    if (blk < 512) {
        __shared__ unsigned short lds[64 * 264];
        const int b = blk >> 6;
        const int row = blk & 63;
        const int p = t & 63;
        const int cb = (t >> 6) * 8;
        const float* xp = x + (size_t)b * CIN * HW + row * WN + p;
#pragma unroll
        for (int i = 0; i < 8; ++i) {
            const int c0 = cb + i * 32;
            float v[8];
#pragma unroll
            for (int j = 0; j < 8; ++j)
                v[j] = xp[(size_t)(c0 + j) * HW];
            uint4 o = { pk2(v[0],v[1]), pk2(v[2],v[3]), pk2(v[4],v[5]), pk2(v[6],v[7]) };
            *(uint4*)&lds[p * 264 + c0] = o;
        }
        __syncthreads();
        unsigned short* op = xh + ((size_t)b * HW + row * WN) * CIN;
#pragma unroll
        for (int i = 0; i < 8; ++i) {
            const int idx = i * 256 + t;
            const int cg = idx & 31, pp = idx >> 5;
            *(uint4*)(op + (size_t)pp * CIN + cg * 8) = *(const uint4*)&lds[pp * 264 + cg * 8];
        }
    } else if (blk < 768) {
        const int cout = blk - 512;
        for (int id = t; id < 288; id += 256) {
            const int k = id * 8;
            const int kk = k >> 8, c0 = k & 255;
            const float* wp = w_dcn + (size_t)cout * KTOT + kk;
            float v[8];
#pragma unroll
            for (int j = 0; j < 8; ++j) v[j] = wp[(size_t)(c0 + j) * NKK];
            uint4 o = { pk2(v[0],v[1]), pk2(v[2],v[3]), pk2(v[4],v[5]), pk2(v[6],v[7]) };
            *(uint4*)(wd_b + (size_t)cout * KTOT + k) = o;
        }
    } else {
        const int r = blk - 768;
        for (int id = t; id < 288; id += 256) {
            const int k = id * 8;
            const int kk = k >> 8, c0 = k & 255;
            uint4 o = {0u, 0u, 0u, 0u};
            if (r < OFFC) {
                const float* wp = w_off + (size_t)r * KTOT + kk;
                float v[8];
#pragma unroll
                for (int j = 0; j < 8; ++j) v[j] = wp[(size_t)(c0 + j) * NKK];
                o = (uint4){ pk2(v[0],v[1]), pk2(v[2],v[3]), pk2(v[4],v[5]), pk2(v[6],v[7]) };
            }
            *(uint4*)(wo_b + (size_t)r * KTOT + k) = o;
        }
    }
}

// ---------------- Stage 1: offsets conv — LDS-free direct-MFMA -------------
__global__ __launch_bounds__(256) void offs_mfma_kernel(
    const unsigned short* __restrict__ xh, const unsigned short* __restrict__ wo_b,
    const float* __restrict__ b_off, float* __restrict__ offs)
{
    const int blk = blockIdx.x;
    const int b = blk & 7;            // XCD swizzle: batch -> XCD
    const int tile = blk >> 3;
    const int ty0 = (tile >> 3) << 3;
    const int tx0 = (tile & 7) << 3;
    const int t = threadIdx.x;
    const int lane = t & 63;
    const int wave = t >> 6;
    const int pxl = wave * 16 + (lane & 15);
    const int kq8 = (lane >> 4) * 8;
    const int oy = ty0 + (pxl >> 3);
    const int ox = tx0 + (pxl & 7);
    const unsigned short* xb = xh + (size_t)b * HW * CIN + kq8;
    const unsigned short* wrow = wo_b + (size_t)(lane & 15) * KTOT + kq8;

    f32x4 acc0 = {0.f,0.f,0.f,0.f}, acc1 = {0.f,0.f,0.f,0.f};
#pragma unroll
    for (int kk = 0; kk < 9; ++kk) {
        const int yy = oy + kk / 3 - 1;
        const int xx = ox + kk % 3 - 1;
        const bool valid = ((unsigned)yy < HN) && ((unsigned)xx < WN);
        const unsigned short* bp = xb + (size_t)(yy * WN + xx) * CIN;
        const unsigned short* wp = wrow + kk * 256;
#pragma unroll
        for (int s = 0; s < 8; ++s) {
            const bf16x8 bfr = valid ? *(const bf16x8*)(bp + s * 32)
                                     : (bf16x8){0,0,0,0,0,0,0,0};
            const bf16x8 a0 = *(const bf16x8*)(wp + s * 32);
            const bf16x8 a1 = *(const bf16x8*)(wp + (size_t)16 * KTOT + s * 32);
            acc0 = __builtin_amdgcn_mfma_f32_16x16x32_bf16(a0, bfr, acc0, 0, 0, 0);
            acc1 = __builtin_amdgcn_mfma_f32_16x16x32_bf16(a1, bfr, acc1, 0, 0, 0);
        }
    }
    const int wy = ty0 + (pxl >> 3), wx = tx0 + (pxl & 7);
#pragma unroll
    for (int j = 0; j < 4; ++j) {
        const int c0 = (lane >> 4) * 4 + j;
        if (c0 < OFFC)
            offs[((size_t)b * OFFC + c0) * HW + wy * WN + wx] = acc0[j] + b_off[c0];
        const int c1 = 16 + c0;
        if (c1 < OFFC)
            offs[((size_t)b * OFFC + c1) * HW + wy * WN + wx] = acc1[j] + b_off[c1];
    }
}

// ---------------- Stage 2: producer/consumer bilinear-gather + MFMA --------
// 1024 thr / 16 waves, 1 block/CU (94.2 KB LDS). Waves 0..11 = producers
// (stage chunk c+1 into samp[(c+1)&1]); waves 12..15 = consumers (GEMM chunk
// c from samp[c&1], 64 couts x 64 px each). One barrier per chunk; loads
// never cross a barrier in flight (m114 wave-level overlap, not source pipelining).
static __device__ __forceinline__ void stage3(
    int t, const unsigned short* __restrict__ xb, int ci0,
    const uint4* __restrict__ tidx, const float4* __restrict__ twgt,
    unsigned short* __restrict__ buf)
{
    // 3 tasks exactly: id = t, t+768, t+1536  (2304 = 768*3)
    int kk[3], px[3], gq[3];
    bf16x8 c[3][4];
#pragma unroll
    for (int r = 0; r < 3; ++r) {
        const int id = r * PROD_T + t;
        kk[r] = id >> 8; px[r] = (id >> 2) & 63; gq[r] = id & 3;
        const uint4 ti = tidx[kk[r] * 64 + px[r]];
        const unsigned short* base = xb + ci0 + gq[r] * 8;
        c[r][0] = *(const bf16x8*)(base + ti.x);
        c[r][1] = *(const bf16x8*)(base + ti.y);
        c[r][2] = *(const bf16x8*)(base + ti.z);
        c[r][3] = *(const bf16x8*)(base + ti.w);
    }
#pragma unroll
    for (int r = 0; r < 3; ++r) {
        const float4 tw = twgt[kk[r] * 64 + px[r]];
        float v[8];
#pragma unroll
        for (int e = 0; e < 8; ++e)
            v[e] = tw.x * bf2f(c[r][0][e]) + tw.y * bf2f(c[r][1][e])
                 + tw.z * bf2f(c[r][2][e]) + tw.w * bf2f(c[r][3][e]);
        uint4 o = { pk2(v[0],v[1]), pk2(v[2],v[3]), pk2(v[4],v[5]), pk2(v[6],v[7]) };
        *(uint4*)&buf[px[r] * SROW + kk[r] * 32 + gq[r] * 8] = o;
    }
}

__global__ __launch_bounds__(1024, 2) void dcn_mfma_kernel(
    const unsigned short* __restrict__ xh, const float* __restrict__ offs,
    const unsigned short* __restrict__ wd_b, const float* __restrict__ bias,
    float* __restrict__ out)
{
    __shared__ unsigned short samp[2][64 * SROW]; // 75,776 B
    __shared__ uint4  tidx[576];                  //  9,216 B
    __shared__ float4 twgt[576];                  //  9,216 B  -> 94,208 B total

    const int blk = blockIdx.x;
    const int b = blk & 7;            // XCD swizzle
    const int tile = blk >> 3;
    const int ty0 = (tile >> 3) << 3;
    const int tx0 = (tile & 7) << 3;
    const int t = threadIdx.x;
    const int lane = t & 63;
    const int wave = t >> 6;
    const bool producer = (wave < 12);
    const unsigned short* xb = xh + (size_t)b * HW * CIN;

    // tap precompute (all waves)
    for (int i = t; i < 576; i += 1024) {
        const int kk = i >> 6, p = i & 63;
        const int oy = ty0 + (p >> 3), ox = tx0 + (p & 7);
        const float offy = offs[((size_t)b * OFFC + 2 * kk) * HW + oy * WN + ox];
        const float offx = offs[((size_t)b * OFFC + 2 * kk + 1) * HW + oy * WN + ox];
        const int ky = kk / 3;
        const float pyf = (float)(oy - 1 + ky) + offy;
        const float pxf = (float)(ox - 1 + (kk - ky * 3)) + offx;
        const float fy0 = floorf(pyf), fx0 = floorf(pxf);
        const int iy0 = (int)fy0, ix0 = (int)fx0;
        const int iy1 = iy0 + 1, ix1 = ix0 + 1;
        const float fy = pyf - fy0, fx = pxf - fx0;
        const float vy0 = ((unsigned)iy0 < HN) ? 1.f : 0.f;
        const float vy1 = ((unsigned)iy1 < HN) ? 1.f : 0.f;
        const float vx0 = ((unsigned)ix0 < WN) ? 1.f : 0.f;
        const float vx1 = ((unsigned)ix1 < WN) ? 1.f : 0.f;
        const int cy0 = min(max(iy0, 0), HN - 1), cy1 = min(max(iy1, 0), HN - 1);
        const int cx0 = min(max(ix0, 0), WN - 1), cx1 = min(max(ix1, 0), WN - 1);
        tidx[i] = make_uint4((unsigned)(cy0 * WN + cx0) * CIN, (unsigned)(cy0 * WN + cx1) * CIN,
                             (unsigned)(cy1 * WN + cx0) * CIN, (unsigned)(cy1 * WN + cx1) * CIN);
        twgt[i] = make_float4((1.f - fy) * (1.f - fx) * vy0 * vx0,
                              (1.f - fy) * fx * vy0 * vx1,
                              fy * (1.f - fx) * vy1 * vx0,
                              fy * fx * vy1 * vx1);
    }
    __syncthreads();   // taps ready

    if (producer) stage3(t, xb, 0, tidx, twgt, samp[0]);
    __syncthreads();   // chunk 0 staged

    const int cw = wave - 12;  // consumer wave id 0..3 (garbage for producers, unused)
    f32x4 acc[4][4];
#pragma unroll
    for (int i = 0; i < 4; ++i)
#pragma unroll
        for (int j = 0; j < 4; ++j) acc[i][j] = (f32x4){0.f, 0.f, 0.f, 0.f};

    const unsigned short* wb0 = wd_b + (size_t)(cw * 64 + (lane & 15)) * KTOT + (lane >> 4) * 8;

    for (int c = 0; c < NCHUNK; ++c) {
        if (producer) {
            if (c < NCHUNK - 1)
                stage3(t, xb, (c + 1) * CICH, tidx, twgt, samp[(c + 1) & 1]);
        } else {
            const unsigned short* sbb = &samp[c & 1][(lane & 15) * SROW + (lane >> 4) * 8];
#pragma unroll
            for (int ct = 0; ct < 4; ++ct) {
                const unsigned short* wp = wb0 + (size_t)ct * 16 * KTOT + c * CICH;
                bf16x8 a[9];
#pragma unroll
                for (int s = 0; s < 9; ++s)
                    a[s] = *(const bf16x8*)(wp + s * 256);
#pragma unroll
                for (int s = 0; s < 9; ++s) {
                    const bf16x8 bfr0 = *(const bf16x8*)(sbb + s * 32);
                    const bf16x8 bfr1 = *(const bf16x8*)(sbb + 16 * SROW + s * 32);
                    const bf16x8 bfr2 = *(const bf16x8*)(sbb + 32 * SROW + s * 32);
                    const bf16x8 bfr3 = *(const bf16x8*)(sbb + 48 * SROW + s * 32);
                    acc[ct][0] = __builtin_amdgcn_mfma_f32_16x16x32_bf16(a[s], bfr0, acc[ct][0], 0, 0, 0);
                    acc[ct][1] = __builtin_amdgcn_mfma_f32_16x16x32_bf16(a[s], bfr1, acc[ct][1], 0, 0, 0);
                    acc[ct][2] = __builtin_amdgcn_mfma_f32_16x16x32_bf16(a[s], bfr2, acc[ct][2], 0, 0, 0);
                    acc[ct][3] = __builtin_amdgcn_mfma_f32_16x16x32_bf16(a[s], bfr3, acc[ct][3], 0, 0, 0);
                }
            }
        }
        __syncthreads();   // buf[(c+1)&1] staged; consumers done with buf[c&1]
    }

    // epilogue: consumers only
    if (!producer) {
        const int row4 = (lane >> 4) * 4;
#pragma unroll
        for (int ct = 0; ct < 4; ++ct) {
            float bv[4];
#pragma unroll
            for (int j = 0; j < 4; ++j) bv[j] = bias[cw * 64 + ct * 16 + row4 + j];
#pragma unroll
            for (int pt = 0; pt < 4; ++pt) {
                const int px = pt * 16 + (lane & 15);
                const int wy = ty0 + (px >> 3), wx = tx0 + (px & 7);
                float* op = out + ((size_t)b * COUT + cw * 64 + ct * 16 + row4) * HW + wy * WN + wx;
#pragma unroll
                for (int j = 0; j < 4; ++j)
                    op[(size_t)j * HW] = acc[ct][pt][j] + bv[j];
            }
        }
    }
}

extern "C" void kernel_launch(void* const* d_in, const int* in_sizes, int n_in,
                              void* d_out, int out_size, void* d_ws, size_t ws_size,
                              hipStream_t stream) {
    const float* x     = (const float*)d_in[0];
    const float* w_off = (const float*)d_in[1];
    const float* b_off = (const float*)d_in[2];
    const float* w_dcn = (const float*)d_in[3];
    const float* b_dcn = (const float*)d_in[4];
    float* out = (float*)d_out;

    // ws: offs fp32 2,359,296 | wd_b 1,179,648 | wo_b 147,456 | xh 16,777,216
    float* offs          = (float*)d_ws;
    unsigned short* wd_b = (unsigned short*)((char*)d_ws + 2359296);
    unsigned short* wo_b = (unsigned short*)((char*)d_ws + 2359296 + 1179648);
    unsigned short* xh   = (unsigned short*)((char*)d_ws + 2359296 + 1179648 + 147456);

    prep_kernel<<<800, 256, 0, stream>>>(x, w_dcn, w_off, xh, wd_b, wo_b);
    offs_mfma_kernel<<<512, 256, 0, stream>>>(xh, wo_b, b_off, offs);
    dcn_mfma_kernel<<<512, 1024, 0, stream>>>(xh, offs, wd_b, b_dcn, out);
}

// Round 10
// 232.369 us; speedup vs baseline: 1.3444x; 1.3444x over previous
//
#include <hip/hip_runtime.h>

#define HN 64
#define WN 64
#define HW 4096
#define CIN 256
#define COUT 256
#define NKK 9
#define OFFC 18
#define KTOT 2304          // 256*9, kk-major: k = kk*256 + c
#define CICH 32
#define SROW 296           // samp row stride bf16 (288+8 pad = 592 B)
#define NCHUNK 8

typedef __attribute__((ext_vector_type(8))) short bf16x8;
typedef __attribute__((ext_vector_type(4))) float f32x4;

// fp32 -> bf16 round-to-nearest-even (finite inputs)
static __device__ __forceinline__ unsigned short f2bf(float f) {
    unsigned u = __float_as_uint(f);
    return (unsigned short)((u + 0x7FFFu + ((u >> 16) & 1u)) >> 16);
}
static __device__ __forceinline__ unsigned pk2(float a, float b) {
    return (unsigned)f2bf(a) | ((unsigned)f2bf(b) << 16);
}
static __device__ __forceinline__ float bf2f(short s) {
    return __uint_as_float(((unsigned)(unsigned short)s) << 16);
}

// ---------------- Stage 0: prep — x -> NHWC bf16 + weight repack -----------
__global__ __launch_bounds__(256) void prep_kernel(
    const float* __restrict__ x, const float* __restrict__ w_dcn,
    const float* __restrict__ w_off, unsigned short* __restrict__ xh,
    unsigned short* __restrict__ wd_b, unsigned short* __restrict__ wo_b)
{
    const int blk = blockIdx.x;
    const int t = threadIdx.x;
    if (blk < 512) {
        __shared__ unsigned short lds[64 * 264];
        const int b = blk >> 6;
        const int row = blk & 63;
        const int p = t & 63;
        const int cb = (t >> 6) * 8;
        const float* xp = x + (size_t)b * CIN * HW + row * WN + p;
#pragma unroll
        for (int i = 0; i < 8; ++i) {
            const int c0 = cb + i * 32;
            float v[8];
#pragma unroll
            for (int j = 0; j < 8; ++j)
                v[j] = xp[(size_t)(c0 + j) * HW];
            uint4 o = { pk2(v[0],v[1]), pk2(v[2],v[3]), pk2(v[4],v[5]), pk2(v[6],v[7]) };
            *(uint4*)&lds[p * 264 + c0] = o;
        }
        __syncthreads();
        unsigned short* op = xh + ((size_t)b * HW + row * WN) * CIN;
#pragma unroll
        for (int i = 0; i < 8; ++i) {
            const int idx = i * 256 + t;
            const int cg = idx & 31, pp = idx >> 5;
            *(uint4*)(op + (size_t)pp * CIN + cg * 8) = *(const uint4*)&lds[pp * 264 + cg * 8];
        }
    } else if (blk < 768) {
        const int cout = blk - 512;
        for (int id = t; id < 288; id += 256) {
            const int k = id * 8;
            const int kk = k >> 8, c0 = k & 255;
            const float* wp = w_dcn + (size_t)cout * KTOT + kk;
            float v[8];
#pragma unroll
            for (int j = 0; j < 8; ++j) v[j] = wp[(size_t)(c0 + j) * NKK];
            uint4 o = { pk2(v[0],v[1]), pk2(v[2],v[3]), pk2(v[4],v[5]), pk2(v[6],v[7]) };
            *(uint4*)(wd_b + (size_t)cout * KTOT + k) = o;
        }
    } else {
        const int r = blk - 768;
        for (int id = t; id < 288; id += 256) {
            const int k = id * 8;
            const int kk = k >> 8, c0 = k & 255;
            uint4 o = {0u, 0u, 0u, 0u};
            if (r < OFFC) {
                const float* wp = w_off + (size_t)r * KTOT + kk;
                float v[8];
#pragma unroll
                for (int j = 0; j < 8; ++j) v[j] = wp[(size_t)(c0 + j) * NKK];
                o = (uint4){ pk2(v[0],v[1]), pk2(v[2],v[3]), pk2(v[4],v[5]), pk2(v[6],v[7]) };
            }
            *(uint4*)(wo_b + (size_t)r * KTOT + k) = o;
        }
    }
}

// ---------------- Stage 1: offsets conv — LDS-free direct-MFMA -------------
__global__ __launch_bounds__(256) void offs_mfma_kernel(
    const unsigned short* __restrict__ xh, const unsigned short* __restrict__ wo_b,
    const float* __restrict__ b_off, float* __restrict__ offs)
{
    const int blk = blockIdx.x;
    const int b = blk & 7;            // XCD swizzle: batch -> XCD
    const int tile = blk >> 3;
    const int ty0 = (tile >> 3) << 3;
    const int tx0 = (tile & 7) << 3;
    const int t = threadIdx.x;
    const int lane = t & 63;
    const int wave = t >> 6;
    const int pxl = wave * 16 + (lane & 15);
    const int kq8 = (lane >> 4) * 8;
    const int oy = ty0 + (pxl >> 3);
    const int ox = tx0 + (pxl & 7);
    const unsigned short* xb = xh + (size_t)b * HW * CIN + kq8;
    const unsigned short* wrow = wo_b + (size_t)(lane & 15) * KTOT + kq8;

    f32x4 acc0 = {0.f,0.f,0.f,0.f}, acc1 = {0.f,0.f,0.f,0.f};
#pragma unroll
    for (int kk = 0; kk < 9; ++kk) {
        const int yy = oy + kk / 3 - 1;
        const int xx = ox + kk % 3 - 1;
        const bool valid = ((unsigned)yy < HN) && ((unsigned)xx < WN);
        const unsigned short* bp = xb + (size_t)(yy * WN + xx) * CIN;
        const unsigned short* wp = wrow + kk * 256;
#pragma unroll
        for (int s = 0; s < 8; ++s) {
            const bf16x8 bfr = valid ? *(const bf16x8*)(bp + s * 32)
                                     : (bf16x8){0,0,0,0,0,0,0,0};
            const bf16x8 a0 = *(const bf16x8*)(wp + s * 32);
            const bf16x8 a1 = *(const bf16x8*)(wp + (size_t)16 * KTOT + s * 32);
            acc0 = __builtin_amdgcn_mfma_f32_16x16x32_bf16(a0, bfr, acc0, 0, 0, 0);
            acc1 = __builtin_amdgcn_mfma_f32_16x16x32_bf16(a1, bfr, acc1, 0, 0, 0);
        }
    }
    const int wy = ty0 + (pxl >> 3), wx = tx0 + (pxl & 7);
#pragma unroll
    for (int j = 0; j < 4; ++j) {
        const int c0 = (lane >> 4) * 4 + j;
        if (c0 < OFFC)
            offs[((size_t)b * OFFC + c0) * HW + wy * WN + wx] = acc0[j] + b_off[c0];
        const int c1 = 16 + c0;
        if (c1 < OFFC)
            offs[((size_t)b * OFFC + c1) * HW + wy * WN + wx] = acc1[j] + b_off[c1];
    }
}

// ---------------- Stage 2: ping-pong bilinear gather + MFMA GEMM -----------
// 1024 thr / 16 waves, 1 block/CU (94.2 KB LDS), launch_bounds(1024,4) ->
// 128-reg budget. Per chunk: issue gathers(c+1) -> combine/write buf^1 ->
// GEMM(c) from buf -> ONE barrier. No load crosses a barrier in flight.
__global__ __launch_bounds__(1024, 4) void dcn_mfma_kernel(
    const unsigned short* __restrict__ xh, const float* __restrict__ offs,
    const unsigned short* __restrict__ wd_b, const float* __restrict__ bias,
    float* __restrict__ out)
{
    __shared__ unsigned short samp[2][64 * SROW]; // 75,776 B
    __shared__ uint4  tidx[576];                  //  9,216 B
    __shared__ float4 twgt[576];                  //  9,216 B -> 94,208 B

    const int blk = blockIdx.x;
    const int b = blk & 7;            // XCD swizzle
    const int tile = blk >> 3;
    const int ty0 = (tile >> 3) << 3;
    const int tx0 = (tile & 7) << 3;
    const int t = threadIdx.x;
    const int lane = t & 63;
    const int wave = t >> 6;
    const unsigned short* xb = xh + (size_t)b * HW * CIN;
    const bool third = (t < 256);

    // tap precompute
    for (int i = t; i < 576; i += 1024) {
        const int kk = i >> 6, p = i & 63;
        const int oy = ty0 + (p >> 3), ox = tx0 + (p & 7);
        const float offy = offs[((size_t)b * OFFC + 2 * kk) * HW + oy * WN + ox];
        const float offx = offs[((size_t)b * OFFC + 2 * kk + 1) * HW + oy * WN + ox];
        const int ky = kk / 3;
        const float pyf = (float)(oy - 1 + ky) + offy;
        const float pxf = (float)(ox - 1 + (kk - ky * 3)) + offx;
        const float fy0 = floorf(pyf), fx0 = floorf(pxf);
        const int iy0 = (int)fy0, ix0 = (int)fx0;
        const int iy1 = iy0 + 1, ix1 = ix0 + 1;
        const float fy = pyf - fy0, fx = pxf - fx0;
        const float vy0 = ((unsigned)iy0 < HN) ? 1.f : 0.f;
        const float vy1 = ((unsigned)iy1 < HN) ? 1.f : 0.f;
        const float vx0 = ((unsigned)ix0 < WN) ? 1.f : 0.f;
        const float vx1 = ((unsigned)ix1 < WN) ? 1.f : 0.f;
        const int cy0 = min(max(iy0, 0), HN - 1), cy1 = min(max(iy1, 0), HN - 1);
        const int cx0 = min(max(ix0, 0), WN - 1), cx1 = min(max(ix1, 0), WN - 1);
        tidx[i] = make_uint4((unsigned)(cy0 * WN + cx0) * CIN, (unsigned)(cy0 * WN + cx1) * CIN,
                             (unsigned)(cy1 * WN + cx0) * CIN, (unsigned)(cy1 * WN + cx1) * CIN);
        twgt[i] = make_float4((1.f - fy) * (1.f - fx) * vy0 * vx0,
                              (1.f - fy) * fx * vy0 * vx1,
                              fy * (1.f - fx) * vy1 * vx0,
                              fy * fx * vy1 * vx1);
    }
    __syncthreads();   // taps ready

    // ---- stage chunk 0 into samp[0] (issue all, then combine all) ----
    {
        bf16x8 g[3][4];
#pragma unroll
        for (int r = 0; r < 3; ++r) {
            if (r == 2 && !third) break;
            const int id = r * 1024 + t;
            const uint4 ti = tidx[(id >> 8) * 64 + ((id >> 2) & 63)];
            const unsigned short* base = xb + (id & 3) * 8;
            g[r][0] = *(const bf16x8*)(base + ti.x);
            g[r][1] = *(const bf16x8*)(base + ti.y);
            g[r][2] = *(const bf16x8*)(base + ti.z);
            g[r][3] = *(const bf16x8*)(base + ti.w);
        }
#pragma unroll
        for (int r = 0; r < 3; ++r) {
            if (r == 2 && !third) break;
            const int id = r * 1024 + t;
            const int kk = id >> 8, px = (id >> 2) & 63, gq = id & 3;
            const float4 tw = twgt[kk * 64 + px];
            float v[8];
#pragma unroll
            for (int e = 0; e < 8; ++e)
                v[e] = tw.x * bf2f(g[r][0][e]) + tw.y * bf2f(g[r][1][e])
                     + tw.z * bf2f(g[r][2][e]) + tw.w * bf2f(g[r][3][e]);
            uint4 o = { pk2(v[0],v[1]), pk2(v[2],v[3]), pk2(v[4],v[5]), pk2(v[6],v[7]) };
            *(uint4*)&samp[0][px * SROW + kk * 32 + gq * 8] = o;
        }
    }
    __syncthreads();   // chunk 0 staged

    f32x4 acc0 = {0.f,0.f,0.f,0.f}, acc1 = {0.f,0.f,0.f,0.f};
    f32x4 acc2 = {0.f,0.f,0.f,0.f}, acc3 = {0.f,0.f,0.f,0.f};

    const unsigned short* wb_base = wd_b + (size_t)(wave * 16 + (lane & 15)) * KTOT
                                  + (lane >> 4) * 8;
    const unsigned short* sb_base = (lane & 15) * SROW + (lane >> 4) * 8
                                  + (const unsigned short*)nullptr - (const unsigned short*)nullptr
                                  + (const unsigned short*)samp[0];  // offset applied per-chunk below
    (void)sb_base;

    for (int c = 0; c < NCHUNK; ++c) {
        const int cur = c & 1;
        // ---- issue gathers for chunk c+1, combine, write to buf^1 ----
        if (c < NCHUNK - 1) {
            const int ci1 = (c + 1) * CICH;
            bf16x8 g[3][4];
#pragma unroll
            for (int r = 0; r < 3; ++r) {
                if (r == 2 && !third) break;
                const int id = r * 1024 + t;
                const uint4 ti = tidx[(id >> 8) * 64 + ((id >> 2) & 63)];
                const unsigned short* base = xb + ci1 + (id & 3) * 8;
                g[r][0] = *(const bf16x8*)(base + ti.x);
                g[r][1] = *(const bf16x8*)(base + ti.y);
                g[r][2] = *(const bf16x8*)(base + ti.z);
                g[r][3] = *(const bf16x8*)(base + ti.w);
            }
#pragma unroll
            for (int r = 0; r < 3; ++r) {
                if (r == 2 && !third) break;
                const int id = r * 1024 + t;
                const int kk = id >> 8, px = (id >> 2) & 63, gq = id & 3;
                const float4 tw = twgt[kk * 64 + px];
                float v[8];
#pragma unroll
                for (int e = 0; e < 8; ++e)
                    v[e] = tw.x * bf2f(g[r][0][e]) + tw.y * bf2f(g[r][1][e])
                         + tw.z * bf2f(g[r][2][e]) + tw.w * bf2f(g[r][3][e]);
                uint4 o = { pk2(v[0],v[1]), pk2(v[2],v[3]), pk2(v[4],v[5]), pk2(v[6],v[7]) };
                *(uint4*)&samp[cur ^ 1][px * SROW + kk * 32 + gq * 8] = o;
            }
        }
        // ---- GEMM chunk c from samp[cur] ----
        const unsigned short* sbb = &samp[cur][(lane & 15) * SROW + (lane >> 4) * 8];
        const unsigned short* wp = wb_base + c * CICH;
#pragma unroll
        for (int s = 0; s < 9; ++s) {
            const bf16x8 a    = *(const bf16x8*)(wp + s * 256);
            const bf16x8 bfr0 = *(const bf16x8*)(sbb + s * 32);
            const bf16x8 bfr1 = *(const bf16x8*)(sbb + 16 * SROW + s * 32);
            const bf16x8 bfr2 = *(const bf16x8*)(sbb + 32 * SROW + s * 32);
            const bf16x8 bfr3 = *(const bf16x8*)(sbb + 48 * SROW + s * 32);
            acc0 = __builtin_amdgcn_mfma_f32_16x16x32_bf16(a, bfr0, acc0, 0, 0, 0);
            acc1 = __builtin_amdgcn_mfma_f32_16x16x32_bf16(a, bfr1, acc1, 0, 0, 0);
            acc2 = __builtin_amdgcn_mfma_f32_16x16x32_bf16(a, bfr2, acc2, 0, 0, 0);
            acc3 = __builtin_amdgcn_mfma_f32_16x16x32_bf16(a, bfr3, acc3, 0, 0, 0);
        }
        __syncthreads();   // buf^1 published; all readers of buf done
    }

    // epilogue
    const int row4 = (lane >> 4) * 4;
    float bv[4];
#pragma unroll
    for (int j = 0; j < 4; ++j) bv[j] = bias[wave * 16 + row4 + j];
    const f32x4 av[4] = {acc0, acc1, acc2, acc3};
#pragma unroll
    for (int pt = 0; pt < 4; ++pt) {
        const int px = pt * 16 + (lane & 15);
        const int wy = ty0 + (px >> 3), wx = tx0 + (px & 7);
        float* op = out + ((size_t)b * COUT + wave * 16 + row4) * HW + wy * WN + wx;
#pragma unroll
        for (int j = 0; j < 4; ++j)
            op[(size_t)j * HW] = av[pt][j] + bv[j];
    }
}

extern "C" void kernel_launch(void* const* d_in, const int* in_sizes, int n_in,
                              void* d_out, int out_size, void* d_ws, size_t ws_size,
                              hipStream_t stream) {
    const float* x     = (const float*)d_in[0];
    const float* w_off = (const float*)d_in[1];
    const float* b_off = (const float*)d_in[2];
    const float* w_dcn = (const float*)d_in[3];
    const float* b_dcn = (const float*)d_in[4];
    float* out = (float*)d_out;

    // ws: offs fp32 2,359,296 | wd_b 1,179,648 | wo_b 147,456 | xh 16,777,216
    float* offs          = (float*)d_ws;
    unsigned short* wd_b = (unsigned short*)((char*)d_ws + 2359296);
    unsigned short* wo_b = (unsigned short*)((char*)d_ws + 2359296 + 1179648);
    unsigned short* xh   = (unsigned short*)((char*)d_ws + 2359296 + 1179648 + 147456);

    prep_kernel<<<800, 256, 0, stream>>>(x, w_dcn, w_off, xh, wd_b, wo_b);
    offs_mfma_kernel<<<512, 256, 0, stream>>>(xh, wo_b, b_off, offs);
    dcn_mfma_kernel<<<512, 1024, 0, stream>>>(xh, offs, wd_b, b_dcn, out);
}